// Round 9
// baseline (294.421 us; speedup 1.0000x reference)
//
#include <hip/hip_runtime.h>
#include <stdint.h>
#include <stddef.h>

typedef __attribute__((ext_vector_type(4))) float f32x4;
typedef __attribute__((ext_vector_type(8))) short bf16x8;

#define BMN 256      // block tile M = N
#define BK  64       // K per K-tile
#define NTHREADS 512

// Round-to-nearest-even fp32 mantissa to 10 bits (shift = 23-10 = 13).
__device__ __forceinline__ float round_m10(float x) {
    int b = __float_as_int(x);
    int rb = ((b >> 13) & 1) + 0x0FFF;
    b = (b + rb) & (int)0xFFFFE000;
    return __int_as_float(b);
}

__device__ __forceinline__ unsigned short f32_to_bf16(float x) {
    unsigned int u = __float_as_uint(x);
    u += 0x7FFFu + ((u >> 16) & 1u);
    return (unsigned short)(u >> 16);
}

// fp32 -> bf16 with the 3-bit bank swizzle BAKED IN: the 16B chunk at logical
// (row, c) is stored at (row, (c & ~7) | ((c&7) ^ (row&7))). Permutation acts
// within each 128B row-window; all tile offsets are 128B-aligned, so LDS
// staging reads LINEARLY and inherits the swizzle (rule #21).
// FUSED single launch for both tensors (x then w) — verified R19.
__global__ void convert2_f32_bf16_swz(const float* __restrict__ inx,
                                      unsigned short* __restrict__ outx,
                                      const float* __restrict__ inw,
                                      unsigned short* __restrict__ outw,
                                      long nx8, long ntot, int cpr) {
    long g = (long)blockIdx.x * blockDim.x + threadIdx.x;
    const long stride = (long)gridDim.x * blockDim.x;
    for (; g < ntot; g += stride) {
        const float* in;
        unsigned short* out;
        long gg;
        if (g < nx8) { in = inx; out = outx; gg = g; }
        else         { in = inw; out = outw; gg = g - nx8; }
        const long row = gg / cpr;
        const int c = (int)(gg - row * cpr);
        const float* p = in + gg * 8;
        f32x4 v0 = *(const f32x4*)p;
        f32x4 v1 = *(const f32x4*)(p + 4);
        bf16x8 o;
        o[0] = (short)f32_to_bf16(v0[0]); o[1] = (short)f32_to_bf16(v0[1]);
        o[2] = (short)f32_to_bf16(v0[2]); o[3] = (short)f32_to_bf16(v0[3]);
        o[4] = (short)f32_to_bf16(v1[0]); o[5] = (short)f32_to_bf16(v1[1]);
        o[6] = (short)f32_to_bf16(v1[2]); o[7] = (short)f32_to_bf16(v1[3]);
        const int cdst = (c & ~7) | ((c & 7) ^ ((int)row & 7));
        *(bf16x8*)(out + (row * (long)cpr + cdst) * 8) = o;
    }
}

__device__ __forceinline__ void gload_lds16(const unsigned short* g, unsigned short* l) {
    __builtin_amdgcn_global_load_lds(
        (const __attribute__((address_space(1))) void*)g,
        (__attribute__((address_space(3))) void*)l, 16, 0, 0);
}

// Stage one 128x64 bf16 half-tile (16 KB): 2 global_load_lds x16 per thread.
// Source is PRE-SWIZZLED, so global read AND LDS dest are perfectly linear.
__device__ __forceinline__ void stage_half(const unsigned short* __restrict__ G,
                                           unsigned short* lds,
                                           int grow0, int gcol, int K, int tid) {
    const int wave = tid >> 6;
#pragma unroll
    for (int p = 0; p < 2; ++p) {
        const int s = tid + p * NTHREADS;            // 16B chunk 0..1023
        const int row = s >> 3;                      // 0..127
        const unsigned short* g = G + (size_t)(grow0 + row) * K + gcol + (s & 7) * 8;
        unsigned short* l = lds + (size_t)(wave * 64 + p * NTHREADS) * 8;
        gload_lds16(g, l);
    }
}

// R22: R13's EXACT phase shape (single barrier, lgkm0, unfenced tail reads
// consumed 1 phase later) with q0+q1 MERGED: 32 MFMA/phase, 4 phases per
// 2-K-tile iteration. Mechanism: the ~460 cyc/phase sync+drain residual is
// paid half as often at unchanged MFMA/LDS totals; the 2x-longer MFMA
// cluster (1242 cyc) also hides the bunched tail-read drain better.
// Ring (audited): P1 stages ALL of buf1(t+1) (8 loads) -> published by
// vmcnt(0)@P2-head (loads 1 full phase old > HBM latency); P3 stages
// buf0(t+2) -> published @P4-head. Cross-buffer tail reads ALWAYS follow
// their publish barrier in program order (P2-tail reads buf1 after P2's
// publish; P4-tail reads buf0 after P4's publish) — stricter than R13.
// Restage-vs-last-reader >= 1 barrier + full MFMA cluster everywhere.
// (Ledger: R13/R19 tail-read 242us MfmaUtil 51.6 = anchor; R14 head-read,
// R20 m201-shape, R21 2-ahead counted, R16/R17 2-barrier: ALL regressed
// 12-35%; 32x32 line closed at R18.)
__global__ __launch_bounds__(NTHREADS, 2)
void gemm8p(const unsigned short* __restrict__ Abf, const unsigned short* __restrict__ Bbf,
            const float* __restrict__ bias, float* __restrict__ out,
            int M, int N, int K) {
    // [buf][half][128 rows][64 k] bf16 (swizzled layout) — 128 KB total
    __shared__ unsigned short sA[2][2][128 * 64];
    __shared__ unsigned short sB[2][2][128 * 64];

    const int tid  = threadIdx.x;
    const int lane = tid & 63;
    const int wave = tid >> 6;
    const int wm = wave >> 2;          // 0..1 : A-half / wave's 128-row band
    const int wn = wave & 3;           // 0..3 : 64-col band (B-half = wn>>1)
    const int lrow = lane & 15;
    const int lkg  = lane >> 4;
    const int NT = K / BK;

    // Bijective XCD-chunk swizzle (T1); grid is (N/256, M/256).
    const int gx = gridDim.x;
    const int nwg = gx * gridDim.y;
    int lin = blockIdx.y * gx + blockIdx.x;
    if ((nwg & 7) == 0) lin = (lin & 7) * (nwg >> 3) + (lin >> 3);
    const int bm0 = (lin / gx) * BMN;
    const int bn0 = (lin % gx) * BMN;

    // Conflict-free fragment-read offsets: phys chunk = logical ^ (lrow&7).
    const int r7   = lrow & 7;
    const int lco0 = (lkg ^ r7) * 8;        // kk = 0
    const int lco1 = lco0 ^ 32;             // kk = 32 (XOR: carry-free)
    const int Aoff0 = lrow * 64 + lco0;
    const int Aoff1 = lrow * 64 + lco1;
    const int Boff0 = ((wn & 1) * 64 + lrow) * 64 + lco0;
    const int Boff1 = ((wn & 1) * 64 + lrow) * 64 + lco1;

    const unsigned short* Ab0 = &sA[0][wm][0];
    const unsigned short* Ab1 = &sA[1][wm][0];
    const unsigned short* Bb0 = &sB[0][wn >> 1][0];
    const unsigned short* Bb1 = &sB[1][wn >> 1][0];

    f32x4 acc[8][4];
    const f32x4 zero = {0.f, 0.f, 0.f, 0.f};
#pragma unroll
    for (int i = 0; i < 8; ++i)
#pragma unroll
        for (int j = 0; j < 4; ++j) acc[i][j] = zero;

    // Merged operand sets, ping-pong per phase: 8 A-frags + 4 B-frags each.
    bf16x8 av0[8], av1[8], bv0[4], bv1[4];

#define RD_A8(dst, base, off) { const unsigned short* _pa = (base); \
    _Pragma("unroll") for (int i = 0; i < 8; ++i) \
        dst[i] = *(const bf16x8*)&_pa[i * 1024 + (off)]; }
#define RD_B4(dst, base, off) { const unsigned short* _pb = (base); \
    _Pragma("unroll") for (int j = 0; j < 4; ++j) \
        dst[j] = *(const bf16x8*)&_pb[j * 1024 + (off)]; }

// R13 phase shape, merged: [STG | VMW? | bar | lgkm0 | 32xMFMA | tail reads].
#define PH4(aU, bU, RDS, STG, VMW) \
    STG \
    VMW \
    __builtin_amdgcn_s_barrier(); \
    asm volatile("s_waitcnt lgkmcnt(0)"); \
    __builtin_amdgcn_sched_barrier(0); \
    __builtin_amdgcn_s_setprio(1); \
    _Pragma("unroll") for (int i = 0; i < 8; ++i) \
    _Pragma("unroll") for (int j = 0; j < 4; ++j) \
        acc[i][j] = __builtin_amdgcn_mfma_f32_16x16x32_bf16(aU[i], bU[j], acc[i][j], 0, 0, 0); \
    __builtin_amdgcn_s_setprio(0); \
    RDS

    // ---- prologue: buf0 <- tile0 (4 halves, 8 loads); drain; publish; read set0.
    stage_half(Abf, &sA[0][0][0], bm0,       0, K, tid);
    stage_half(Abf, &sA[0][1][0], bm0 + 128, 0, K, tid);
    stage_half(Bbf, &sB[0][0][0], bn0,       0, K, tid);
    stage_half(Bbf, &sB[0][1][0], bn0 + 128, 0, K, tid);
    asm volatile("s_waitcnt vmcnt(0)");
    __builtin_amdgcn_s_barrier();
    RD_A8(av0, Ab0, Aoff0)
    RD_B4(bv0, Bb0, Boff0)

    // ---- main loop: 2 K-tiles per iteration (buf0 = t, buf1 = t+1).
    // vmcnt audit: max 8 outstanding; each vmcnt(0) drains loads exactly one
    // full phase (~1600+ cyc) old — beyond the ~900 cyc HBM-miss latency.
    for (int t = 0; t < NT; t += 2) {
        int u2 = t + 2; if (u2 >= NT) u2 -= NT;   // wrap stage = harmless dummy
        const int k1 = (t + 1) * BK, k2 = u2 * BK;

        // P1: MFMA buf0 kk0 [set0]; stage buf1 <- t+1 (8 loads);
        //     tail: set1 <- buf0 kk32
        PH4(av0, bv0,
            RD_A8(av1, Ab0, Aoff1) RD_B4(bv1, Bb0, Boff1),
            stage_half(Abf, &sA[1][0][0], bm0,       k1, K, tid);
            stage_half(Abf, &sA[1][1][0], bm0 + 128, k1, K, tid);
            stage_half(Bbf, &sB[1][0][0], bn0,       k1, K, tid);
            stage_half(Bbf, &sB[1][1][0], bn0 + 128, k1, K, tid);, )

        // P2: vmcnt(0) drains P1's 8 -> publish buf1(t+1); MFMA buf0 kk32
        //     [set1]; tail: set0 <- buf1 kk0 (after publish barrier: SAFE)
        PH4(av1, bv1,
            RD_A8(av0, Ab1, Aoff0) RD_B4(bv0, Bb1, Boff0),
            , asm volatile("s_waitcnt vmcnt(0)");)

        // P3: MFMA buf1 kk0 [set0]; stage buf0 <- t+2 (8 loads);
        //     tail: set1 <- buf1 kk32
        PH4(av0, bv0,
            RD_A8(av1, Ab1, Aoff1) RD_B4(bv1, Bb1, Boff1),
            stage_half(Abf, &sA[0][0][0], bm0,       k2, K, tid);
            stage_half(Abf, &sA[0][1][0], bm0 + 128, k2, K, tid);
            stage_half(Bbf, &sB[0][0][0], bn0,       k2, K, tid);
            stage_half(Bbf, &sB[0][1][0], bn0 + 128, k2, K, tid);, )

        // P4: vmcnt(0) drains P3's 8 -> publish buf0(t+2); MFMA buf1 kk32
        //     [set1]; tail: set0 <- buf0 kk0 (next iter; after publish: SAFE)
        PH4(av1, bv1,
            RD_A8(av0, Ab0, Aoff0) RD_B4(bv0, Bb0, Boff0),
            , asm volatile("s_waitcnt vmcnt(0)");)
    }

    asm volatile("s_waitcnt vmcnt(0) lgkmcnt(0)" ::: "memory");  // drain

    // ---- epilogue: + bias, final mantissa round, store fp32.
    // C/D layout (verified m89/m91): row = lkg*4 + reg, col = lrow.
#pragma unroll
    for (int ia = 0; ia < 8; ++ia) {
        const int row = bm0 + wm * 128 + ia * 16 + lkg * 4;
#pragma unroll
        for (int j = 0; j < 4; ++j) {
            const int col = bn0 + wn * 64 + j * 16 + lrow;
            const float bv = bias[col];
#pragma unroll
            for (int r = 0; r < 4; ++r)
                out[(size_t)(row + r) * N + col] = round_m10(acc[ia][j][r] + bv);
        }
    }
#undef RD_A8
#undef RD_B4
#undef PH4
}

// Fallback: fused fp32->bf16 128^2 kernel (only for shapes the main path rejects).
__global__ __launch_bounds__(256)
void gemm_fallback(const float* __restrict__ A, const float* __restrict__ B,
                   const float* __restrict__ bias, float* __restrict__ out,
                   int M, int N, int K) {
    __shared__ unsigned short lds_a[128 * 64];
    __shared__ unsigned short lds_b[128 * 64];
    const int tid = threadIdx.x, lane = tid & 63, wave = tid >> 6;
    const int wm = wave >> 1, wn = wave & 1;
    const int bm0 = blockIdx.y * 128, bn0 = blockIdx.x * 128;
    const int lrow = lane & 15, lkg = lane >> 4;
    f32x4 acc[4][4];
    const f32x4 zero = {0.f, 0.f, 0.f, 0.f};
#pragma unroll
    for (int i = 0; i < 4; ++i)
#pragma unroll
        for (int j = 0; j < 4; ++j) acc[i][j] = zero;
    for (int kb = 0; kb < K / 64; ++kb) {
        const int kt = kb * 64;
        const int r0 = tid >> 4, c0 = (tid & 15) << 2;
#pragma unroll
        for (int p = 0; p < 8; ++p) {
            const int r = p * 16 + r0;
            f32x4 va = *(const f32x4*)(A + (size_t)(bm0 + r) * K + kt + c0);
            f32x4 vb = *(const f32x4*)(B + (size_t)(bn0 + r) * K + kt + c0);
            ushort4 ua, ub;
            ua.x = f32_to_bf16(va[0]); ua.y = f32_to_bf16(va[1]);
            ua.z = f32_to_bf16(va[2]); ua.w = f32_to_bf16(va[3]);
            ub.x = f32_to_bf16(vb[0]); ub.y = f32_to_bf16(vb[1]);
            ub.z = f32_to_bf16(vb[2]); ub.w = f32_to_bf16(vb[3]);
            *(ushort4*)(&lds_a[r * 64 + c0]) = ua;
            *(ushort4*)(&lds_b[r * 64 + c0]) = ub;
        }
        __syncthreads();
#pragma unroll
        for (int kk = 0; kk < 64; kk += 32) {
            bf16x8 af[4], bfr[4];
#pragma unroll
            for (int i = 0; i < 4; ++i)
                af[i] = *(const bf16x8*)(&lds_a[(wm * 64 + i * 16 + lrow) * 64 + kk + lkg * 8]);
#pragma unroll
            for (int j = 0; j < 4; ++j)
                bfr[j] = *(const bf16x8*)(&lds_b[(wn * 64 + j * 16 + lrow) * 64 + kk + lkg * 8]);
#pragma unroll
            for (int i = 0; i < 4; ++i)
#pragma unroll
                for (int j = 0; j < 4; ++j)
                    acc[i][j] = __builtin_amdgcn_mfma_f32_16x16x32_bf16(af[i], bfr[j], acc[i][j], 0, 0, 0);
        }
        __syncthreads();
    }
#pragma unroll
    for (int i = 0; i < 4; ++i) {
        const int row0 = bm0 + wm * 64 + i * 16 + lkg * 4;
#pragma unroll
        for (int j = 0; j < 4; ++j) {
            const int col = bn0 + wn * 64 + j * 16 + lrow;
            const float bv = bias[col];
#pragma unroll
            for (int r = 0; r < 4; ++r)
                out[(size_t)(row0 + r) * N + col] = round_m10(acc[i][j][r] + bv);
        }
    }
}

extern "C" void kernel_launch(void* const* d_in, const int* in_sizes, int n_in,
                              void* d_out, int out_size, void* d_ws, size_t ws_size,
                              hipStream_t stream) {
    const float* x    = (const float*)d_in[0];   // [M, K]
    const float* w    = (const float*)d_in[1];   // [N, K]
    const float* bias = (const float*)d_in[2];   // [N]
    float* out = (float*)d_out;                  // [M, N]

    const int N = in_sizes[2];
    const int K = in_sizes[1] / N;
    const int M = in_sizes[0] / K;

    const size_t nx = (size_t)M * K;
    const size_t nw = (size_t)N * K;
    const size_t need = (nx + nw) * sizeof(unsigned short);
    const int NT = K / BK;

    if (ws_size >= need && (M % BMN) == 0 && (N % BMN) == 0 && (K % BK) == 0 &&
        NT >= 4 && (NT % 2) == 0) {
        unsigned short* xb = (unsigned short*)d_ws;
        unsigned short* wb = xb + nx;
        const int cpr = K / 8;
        convert2_f32_bf16_swz<<<2048, 256, 0, stream>>>(
            x, xb, w, wb, (long)(nx / 8), (long)((nx + nw) / 8), cpr);
        dim3 grid(N / BMN, M / BMN);
        gemm8p<<<grid, NTHREADS, 0, stream>>>(xb, wb, bias, out, M, N, K);
    } else {
        dim3 grid(N / 128, M / 128);
        gemm_fallback<<<grid, 256, 0, stream>>>(x, w, bias, out, M, N, K);
    }
}

// Round 10
// 271.537 us; speedup vs baseline: 1.0843x; 1.0843x over previous
//
#include <hip/hip_runtime.h>
#include <stdint.h>
#include <stddef.h>

typedef __attribute__((ext_vector_type(4))) float f32x4;
typedef __attribute__((ext_vector_type(8))) short bf16x8;

#define BMN 256      // block tile M = N
#define BK  64       // K per K-tile
#define NTHREADS 512

// Round-to-nearest-even fp32 mantissa to 10 bits (shift = 23-10 = 13).
__device__ __forceinline__ float round_m10(float x) {
    int b = __float_as_int(x);
    int rb = ((b >> 13) & 1) + 0x0FFF;
    b = (b + rb) & (int)0xFFFFE000;
    return __int_as_float(b);
}

__device__ __forceinline__ unsigned short f32_to_bf16(float x) {
    unsigned int u = __float_as_uint(x);
    u += 0x7FFFu + ((u >> 16) & 1u);
    return (unsigned short)(u >> 16);
}

// fp32 -> bf16 with the 3-bit bank swizzle BAKED IN: the 16B chunk at logical
// (row, c) is stored at (row, (c & ~7) | ((c&7) ^ (row&7))). Permutation acts
// within each 128B row-window; all tile offsets are 128B-aligned, so LDS
// staging reads LINEARLY and inherits the swizzle (rule #21).
// FUSED single launch for both tensors (x then w) — verified R19 (+4.6us).
__global__ void convert2_f32_bf16_swz(const float* __restrict__ inx,
                                      unsigned short* __restrict__ outx,
                                      const float* __restrict__ inw,
                                      unsigned short* __restrict__ outw,
                                      long nx8, long ntot, int cpr) {
    long g = (long)blockIdx.x * blockDim.x + threadIdx.x;
    const long stride = (long)gridDim.x * blockDim.x;
    for (; g < ntot; g += stride) {
        const float* in;
        unsigned short* out;
        long gg;
        if (g < nx8) { in = inx; out = outx; gg = g; }
        else         { in = inw; out = outw; gg = g - nx8; }
        const long row = gg / cpr;
        const int c = (int)(gg - row * cpr);
        const float* p = in + gg * 8;
        f32x4 v0 = *(const f32x4*)p;
        f32x4 v1 = *(const f32x4*)(p + 4);
        bf16x8 o;
        o[0] = (short)f32_to_bf16(v0[0]); o[1] = (short)f32_to_bf16(v0[1]);
        o[2] = (short)f32_to_bf16(v0[2]); o[3] = (short)f32_to_bf16(v0[3]);
        o[4] = (short)f32_to_bf16(v1[0]); o[5] = (short)f32_to_bf16(v1[1]);
        o[6] = (short)f32_to_bf16(v1[2]); o[7] = (short)f32_to_bf16(v1[3]);
        const int cdst = (c & ~7) | ((c & 7) ^ ((int)row & 7));
        *(bf16x8*)(out + (row * (long)cpr + cdst) * 8) = o;
    }
}

__device__ __forceinline__ void gload_lds16(const unsigned short* g, unsigned short* l) {
    __builtin_amdgcn_global_load_lds(
        (const __attribute__((address_space(1))) void*)g,
        (__attribute__((address_space(3))) void*)l, 16, 0, 0);
}

// Stage one 128x64 bf16 half-tile (16 KB): 2 global_load_lds x16 per thread.
// Source is PRE-SWIZZLED, so global read AND LDS dest are perfectly linear.
__device__ __forceinline__ void stage_half(const unsigned short* __restrict__ G,
                                           unsigned short* lds,
                                           int grow0, int gcol, int K, int tid) {
    const int wave = tid >> 6;
#pragma unroll
    for (int p = 0; p < 2; ++p) {
        const int s = tid + p * NTHREADS;            // 16B chunk 0..1023
        const int row = s >> 3;                      // 0..127
        const unsigned short* g = G + (size_t)(grow0 + row) * K + gcol + (s & 7) * 8;
        unsigned short* l = lds + (size_t)(wave * 64 + p * NTHREADS) * 8;
        gload_lds16(g, l);
    }
}

// R13 single-barrier 8-phase + READ-AHEAD: phase p's operands were read in
// phase p-1's POST-barrier region (during MFMA), so the LDS queue drains
// under the matrix pipe. Phase = [stage|vmcnt?] barrier [lgkm0|MFMA|read p+1].
//
// ===== CLOSED-LINE LEDGER (do not re-open without new counter evidence) ====
// Anchor (this shape): gemm 242-244us, MfmaUtil 50.3-51.6, conflicts 0.
//   R14 head-read + sched_barrier pins ...... 285us / MfmaUtil 41  (WORSE)
//   R15 32x32, loose tail-reads ............. RACED post-timing
//   R16 32x32, 2-barrier airtight ........... 320us / 37  + 2.5e7 conflicts
//   R17 32x32, pinned loose ................. 313us / 37.6 + 2.5e7 conflicts
//       (conflicts identical across R16/R17 -> caused by the 32x32 fragment
//        read pattern itself, not scheduling)
//   R18 32x32, fragment-order LDS ........... 276us / 44.4, conflicts 0
//       -> 32x32 intrinsically ~30us worse here; line closed
//   R20 m201-style same-phase reads ......... 310us / 37.8 (3rd 2-barrier fail)
//   R21 2-phase-ahead counted lgkm .......... 295us / 40.5
//   R22 merged q0+q1 (4 phases, 32 MFMA) .... 276us / 43.3
// Law: single barrier/phase; reads issued in the UNFENCED post-MFMA tail;
// consumed exactly 1 phase later via lgkmcnt(0). Any deviation loses 12-35%.
// ===========================================================================
__global__ __launch_bounds__(NTHREADS, 2)
void gemm8p(const unsigned short* __restrict__ Abf, const unsigned short* __restrict__ Bbf,
            const float* __restrict__ bias, float* __restrict__ out,
            int M, int N, int K) {
    // [buf][half][128 rows][64 k] bf16 (swizzled layout) — 128 KB total
    __shared__ unsigned short sA[2][2][128 * 64];
    __shared__ unsigned short sB[2][2][128 * 64];

    const int tid  = threadIdx.x;
    const int lane = tid & 63;
    const int wave = tid >> 6;
    const int wm = wave >> 2;          // 0..1 : A-half / wave's 128-row band
    const int wn = wave & 3;           // 0..3 : 64-col band (B-half = wn>>1)
    const int lrow = lane & 15;
    const int lkg  = lane >> 4;
    const int NT = K / BK;

    // Bijective XCD-chunk swizzle (T1); grid is (N/256, M/256).
    const int gx = gridDim.x;
    const int nwg = gx * gridDim.y;
    int lin = blockIdx.y * gx + blockIdx.x;
    if ((nwg & 7) == 0) lin = (lin & 7) * (nwg >> 3) + (lin >> 3);
    const int bm0 = (lin / gx) * BMN;
    const int bn0 = (lin % gx) * BMN;

    // Conflict-free fragment-read offsets: phys chunk = logical ^ (lrow&7).
    const int r7   = lrow & 7;
    const int lco0 = (lkg ^ r7) * 8;        // kk = 0
    const int lco1 = lco0 ^ 32;             // kk = 32 (XOR: carry-free)
    const int Aoff0 = lrow * 64 + lco0;
    const int Aoff1 = lrow * 64 + lco1;
    const int Boff0 = ((wn & 1) * 64 + lrow) * 64 + lco0;
    const int Boff1 = ((wn & 1) * 64 + lrow) * 64 + lco1;

    const unsigned short* Ab0 = &sA[0][wm][0];
    const unsigned short* Ab1 = &sA[1][wm][0];
    const unsigned short* Bb0 = &sB[0][wn >> 1][0];
    const unsigned short* Bb1 = &sB[1][wn >> 1][0];

    f32x4 acc[8][4];
    const f32x4 zero = {0.f, 0.f, 0.f, 0.f};
#pragma unroll
    for (int i = 0; i < 8; ++i)
#pragma unroll
        for (int j = 0; j < 4; ++j) acc[i][j] = zero;

    // Ping-pong operand sets: A alternates per phase; B per 2 phases.
    bf16x8 aS0[4], aS1[4], bS0[4], bS1[4];

#define RD_A(dst, base, q, off) { const unsigned short* _pa = (base); \
    _Pragma("unroll") for (int i = 0; i < 4; ++i) \
        dst[i] = *(const bf16x8*)&_pa[((q) * 4 + i) * 1024 + (off)]; }
#define RD_B(dst, base, off) { const unsigned short* _pb = (base); \
    _Pragma("unroll") for (int j = 0; j < 4; ++j) \
        dst[j] = *(const bf16x8*)&_pb[j * 1024 + (off)]; }

// Single barrier per phase; reads for NEXT phase issued after this MFMA.
#define PH(q, aU, bU, RDS, STG, VMW) \
    STG \
    VMW \
    __builtin_amdgcn_s_barrier(); \
    asm volatile("s_waitcnt lgkmcnt(0)"); \
    __builtin_amdgcn_sched_barrier(0); \
    __builtin_amdgcn_s_setprio(1); \
    _Pragma("unroll") for (int i = 0; i < 4; ++i) \
    _Pragma("unroll") for (int j = 0; j < 4; ++j) \
        acc[(q) * 4 + i][j] = __builtin_amdgcn_mfma_f32_16x16x32_bf16(aU[i], bU[j], acc[(q) * 4 + i][j], 0, 0, 0); \
    __builtin_amdgcn_s_setprio(0); \
    RDS

    // ---- prologue: tile0 (4 halves) + tile1 B-halves; counted wait, no drain.
    stage_half(Abf, &sA[0][0][0], bm0,       0,  K, tid);
    stage_half(Abf, &sA[0][1][0], bm0 + 128, 0,  K, tid);
    stage_half(Bbf, &sB[0][0][0], bn0,       0,  K, tid);
    stage_half(Bbf, &sB[0][1][0], bn0 + 128, 0,  K, tid);
    stage_half(Bbf, &sB[1][0][0], bn0,       BK, K, tid);
    stage_half(Bbf, &sB[1][1][0], bn0 + 128, BK, K, tid);
    asm volatile("s_waitcnt vmcnt(4)");      // tile0's 8 loads landed
    __builtin_amdgcn_s_barrier();
    // P1's operands (tile0, landed & published above)
    RD_A(aS0, Ab0, 0, Aoff0)
    RD_B(bS0, Bb0, Boff0)

    // ---- main loop: 2 K-tiles per iteration (buf0 = t, buf1 = t+1).
    // Stage ring (R13-exact): A0A1(t+1)@P1P2, B0B1A0A1(t+2)@P4-P7, B0B1(t+3)@P8.
    // vmcnt(2)@P4 / vmcnt(4)@P8 precede the barrier that publishes the buffer;
    // the reads of that buffer are in the SAME phase's post-region (after it).
    for (int t = 0; t < NT; t += 2) {
        int u2 = t + 2; if (u2 >= NT) u2 -= NT;   // wrap stages = harmless dummies
        int u3 = t + 3; if (u3 >= NT) u3 -= NT;
        const int k1 = (t + 1) * BK, k2 = u2 * BK, k3 = u3 * BK;

        // P1: MFMA tile t, kk=0, q0; read P2 ops
        PH(0, aS0, bS0,
           RD_A(aS1, Ab0, 1, Aoff0),
           stage_half(Abf, &sA[1][0][0], bm0, k1, K, tid);, )

        // P2: q1; read P3 ops
        PH(1, aS1, bS0,
           RD_A(aS0, Ab0, 0, Aoff1) RD_B(bS1, Bb0, Boff1),
           stage_half(Abf, &sA[1][1][0], bm0 + 128, k1, K, tid);, )

        // P3: kk=32, q0; read P4 ops (no stage)
        PH(0, aS0, bS1,
           RD_A(aS1, Ab0, 1, Aoff1), , )

        // P4: q1; vmcnt(2) publishes tile t+1; read P5 ops (buf1) post-barrier
        PH(1, aS1, bS1,
           RD_A(aS0, Ab1, 0, Aoff0) RD_B(bS0, Bb1, Boff0),
           stage_half(Bbf, &sB[0][0][0], bn0, k2, K, tid);,
           asm volatile("s_waitcnt vmcnt(2)");)

        // P5: tile t+1, kk=0, q0; read P6 ops
        PH(0, aS0, bS0,
           RD_A(aS1, Ab1, 1, Aoff0),
           stage_half(Bbf, &sB[0][1][0], bn0 + 128, k2, K, tid);, )

        // P6: q1; read P7 ops
        PH(1, aS1, bS0,
           RD_A(aS0, Ab1, 0, Aoff1) RD_B(bS1, Bb1, Boff1),
           stage_half(Abf, &sA[0][0][0], bm0, k2, K, tid);, )

        // P7: kk=32, q0; read P8 ops
        PH(0, aS0, bS1,
           RD_A(aS1, Ab1, 1, Aoff1),
           stage_half(Abf, &sA[0][1][0], bm0 + 128, k2, K, tid);, )

        // P8: q1; vmcnt(4) publishes tile t+2 (buf0); read next-P1 ops post-bar
        PH(1, aS1, bS1,
           RD_A(aS0, Ab0, 0, Aoff0) RD_B(bS0, Bb0, Boff0),
           stage_half(Bbf, &sB[1][0][0], bn0, k3, K, tid);
           stage_half(Bbf, &sB[1][1][0], bn0 + 128, k3, K, tid);,
           asm volatile("s_waitcnt vmcnt(4)");)
    }

    asm volatile("s_waitcnt vmcnt(0) lgkmcnt(0)" ::: "memory");  // drain

    // ---- epilogue: + bias, final mantissa round, store fp32.
    // C/D layout (verified m89/m91): row = lkg*4 + reg, col = lrow.
#pragma unroll
    for (int ia = 0; ia < 8; ++ia) {
        const int row = bm0 + wm * 128 + ia * 16 + lkg * 4;
#pragma unroll
        for (int j = 0; j < 4; ++j) {
            const int col = bn0 + wn * 64 + j * 16 + lrow;
            const float bv = bias[col];
#pragma unroll
            for (int r = 0; r < 4; ++r)
                out[(size_t)(row + r) * N + col] = round_m10(acc[ia][j][r] + bv);
        }
    }
#undef RD_A
#undef RD_B
#undef PH
}

// Fallback: fused fp32->bf16 128^2 kernel (only for shapes the main path rejects).
__global__ __launch_bounds__(256)
void gemm_fallback(const float* __restrict__ A, const float* __restrict__ B,
                   const float* __restrict__ bias, float* __restrict__ out,
                   int M, int N, int K) {
    __shared__ unsigned short lds_a[128 * 64];
    __shared__ unsigned short lds_b[128 * 64];
    const int tid = threadIdx.x, lane = tid & 63, wave = tid >> 6;
    const int wm = wave >> 1, wn = wave & 1;
    const int bm0 = blockIdx.y * 128, bn0 = blockIdx.x * 128;
    const int lrow = lane & 15, lkg = lane >> 4;
    f32x4 acc[4][4];
    const f32x4 zero = {0.f, 0.f, 0.f, 0.f};
#pragma unroll
    for (int i = 0; i < 4; ++i)
#pragma unroll
        for (int j = 0; j < 4; ++j) acc[i][j] = zero;
    for (int kb = 0; kb < K / 64; ++kb) {
        const int kt = kb * 64;
        const int r0 = tid >> 4, c0 = (tid & 15) << 2;
#pragma unroll
        for (int p = 0; p < 8; ++p) {
            const int r = p * 16 + r0;
            f32x4 va = *(const f32x4*)(A + (size_t)(bm0 + r) * K + kt + c0);
            f32x4 vb = *(const f32x4*)(B + (size_t)(bn0 + r) * K + kt + c0);
            ushort4 ua, ub;
            ua.x = f32_to_bf16(va[0]); ua.y = f32_to_bf16(va[1]);
            ua.z = f32_to_bf16(va[2]); ua.w = f32_to_bf16(va[3]);
            ub.x = f32_to_bf16(vb[0]); ub.y = f32_to_bf16(vb[1]);
            ub.z = f32_to_bf16(vb[2]); ub.w = f32_to_bf16(vb[3]);
            *(ushort4*)(&lds_a[r * 64 + c0]) = ua;
            *(ushort4*)(&lds_b[r * 64 + c0]) = ub;
        }
        __syncthreads();
#pragma unroll
        for (int kk = 0; kk < 64; kk += 32) {
            bf16x8 af[4], bfr[4];
#pragma unroll
            for (int i = 0; i < 4; ++i)
                af[i] = *(const bf16x8*)(&lds_a[(wm * 64 + i * 16 + lrow) * 64 + kk + lkg * 8]);
#pragma unroll
            for (int j = 0; j < 4; ++j)
                bfr[j] = *(const bf16x8*)(&lds_b[(wn * 64 + j * 16 + lrow) * 64 + kk + lkg * 8]);
#pragma unroll
            for (int i = 0; i < 4; ++i)
#pragma unroll
                for (int j = 0; j < 4; ++j)
                    acc[i][j] = __builtin_amdgcn_mfma_f32_16x16x32_bf16(af[i], bfr[j], acc[i][j], 0, 0, 0);
        }
        __syncthreads();
    }
#pragma unroll
    for (int i = 0; i < 4; ++i) {
        const int row0 = bm0 + wm * 64 + i * 16 + lkg * 4;
#pragma unroll
        for (int j = 0; j < 4; ++j) {
            const int col = bn0 + wn * 64 + j * 16 + lrow;
            const float bv = bias[col];
#pragma unroll
            for (int r = 0; r < 4; ++r)
                out[(size_t)(row0 + r) * N + col] = round_m10(acc[i][j][r] + bv);
        }
    }
}

extern "C" void kernel_launch(void* const* d_in, const int* in_sizes, int n_in,
                              void* d_out, int out_size, void* d_ws, size_t ws_size,
                              hipStream_t stream) {
    const float* x    = (const float*)d_in[0];   // [M, K]
    const float* w    = (const float*)d_in[1];   // [N, K]
    const float* bias = (const float*)d_in[2];   // [N]
    float* out = (float*)d_out;                  // [M, N]

    const int N = in_sizes[2];
    const int K = in_sizes[1] / N;
    const int M = in_sizes[0] / K;

    const size_t nx = (size_t)M * K;
    const size_t nw = (size_t)N * K;
    const size_t need = (nx + nw) * sizeof(unsigned short);
    const int NT = K / BK;

    if (ws_size >= need && (M % BMN) == 0 && (N % BMN) == 0 && (K % BK) == 0 &&
        NT >= 4 && (NT % 2) == 0) {
        unsigned short* xb = (unsigned short*)d_ws;
        unsigned short* wb = xb + nx;
        const int cpr = K / 8;
        convert2_f32_bf16_swz<<<2048, 256, 0, stream>>>(
            x, xb, w, wb, (long)(nx / 8), (long)((nx + nw) / 8), cpr);
        dim3 grid(N / BMN, M / BMN);
        gemm8p<<<grid, NTHREADS, 0, stream>>>(xb, wb, bias, out, M, N, K);
    } else {
        dim3 grid(N / 128, M / 128);
        gemm_fallback<<<grid, 256, 0, stream>>>(x, w, bias, out, M, N, K);
    }
}